// Round 1
// baseline (1035.908 us; speedup 1.0000x reference)
//
#include <hip/hip_runtime.h>
#include <stdint.h>

#define T_TOK 1024
#define HID   2048
#define NE    8
#define INTER 5632
#define I2    11264
#define BM    64
#define BN    128
#define BK    64
#define MAXTILES 40
#define RMAX  2560

typedef __bf16 bf16x8 __attribute__((ext_vector_type(8)));
typedef float  f32x4  __attribute__((ext_vector_type(4)));
typedef unsigned short u16;
typedef u16 u16x4 __attribute__((ext_vector_type(4)));
typedef u16 u16x8 __attribute__((ext_vector_type(8)));

// meta layout (int view unless noted):
// [0..8)    counts[e]
// [8..16)   run[e]
// [16]      ntiles
// [24..32)  slotoff[e]
// [32..112) tiles: {expert, row_base} x MAXTILES
// [256..2304)  toke: {e0,e1} per token
// [2560..5120) rowtok[slot]
// float view:
// [5632..8192)  roww[slot]
// [8192..10240) tokw: {w0,w1} per token
// act buffer (bf16) at byte offset 65536: RMAX x INTER

__device__ __forceinline__ u16 f2bf(float f) {
    uint32_t u = __builtin_bit_cast(uint32_t, f);
    u += 0x7fffu + ((u >> 16) & 1u);
    return (u16)(u >> 16);
}

__global__ void moe_router(const float* __restrict__ logits,
                           int* __restrict__ mi, float* __restrict__ mf) {
    int t = blockIdx.x * blockDim.x + threadIdx.x;
    if (t >= T_TOK) return;
    float l[NE];
#pragma unroll
    for (int i = 0; i < NE; ++i) l[i] = logits[t * NE + i];
    int e0 = 0; float v0 = l[0];
#pragma unroll
    for (int i = 1; i < NE; ++i) if (l[i] > v0) { v0 = l[i]; e0 = i; }
    int e1 = -1; float v1 = -3.4e38f;
#pragma unroll
    for (int i = 0; i < NE; ++i) if (i != e0 && l[i] > v1) { v1 = l[i]; e1 = i; }
    float ex = __expf(v1 - v0);          // <= 1
    float s  = 1.f + ex;
    float w0 = 1.f / s, w1 = ex / s;     // normalized top-2 softmax weights
    mi[256 + 2 * t]     = e0;
    mi[256 + 2 * t + 1] = e1;
    mf[8192 + 2 * t]     = w0;
    mf[8192 + 2 * t + 1] = w1;
    atomicAdd(&mi[e0], 1);
    atomicAdd(&mi[e1], 1);
}

__global__ void moe_plan(int* __restrict__ mi) {
    int tid = threadIdx.x;
    if (tid == 0) {
        int off = 0, nt = 0;
        for (int e = 0; e < NE; ++e) {
            int c = mi[e];
            mi[24 + e] = off;            // slotoff
            int ntile = (c + BM - 1) / BM;
            for (int j = 0; j < ntile; ++j) {
                mi[32 + 2 * nt]     = e;
                mi[32 + 2 * nt + 1] = off + j * BM;
                ++nt;
            }
            off += ntile * BM;
            mi[8 + e] = 0;               // run
        }
        mi[16] = nt;
    }
    for (int i = tid; i < RMAX; i += blockDim.x) mi[2560 + i] = -1;
}

__global__ void moe_scatter(int* __restrict__ mi, float* __restrict__ mf) {
    int t = blockIdx.x * blockDim.x + threadIdx.x;
    if (t >= T_TOK) return;
    int e0 = mi[256 + 2 * t], e1 = mi[256 + 2 * t + 1];
    float w0 = mf[8192 + 2 * t], w1 = mf[8192 + 2 * t + 1];
    int p0 = atomicAdd(&mi[8 + e0], 1);
    int s0 = mi[24 + e0] + p0;
    mi[2560 + s0] = t; mf[5632 + s0] = w0;
    int p1 = atomicAdd(&mi[8 + e1], 1);
    int s1 = mi[24 + e1] + p1;
    mi[2560 + s1] = t; mf[5632 + s1] = w1;
}

// GEMM1: act[slot, i] = silu(X W13_gate^T) * (X W13_up^T), X rows gathered by slot
__global__ __launch_bounds__(256) void moe_gemm1(
        const float* __restrict__ hidden, const float* __restrict__ w13,
        const int* __restrict__ mi, u16* __restrict__ act) {
    const int tj = blockIdx.x, ct = blockIdx.y;
    if (tj >= mi[16]) return;
    const int e = mi[32 + 2 * tj], row_base = mi[32 + 2 * tj + 1];
    const int* rowtok = mi + 2560;

    __shared__ u16 As[BM * 72];
    __shared__ u16 Bgs[BN * 72];
    __shared__ u16 Bus[BN * 72];
    __shared__ int toks[BM];

    const int tid = threadIdx.x;
    if (tid < BM) toks[tid] = rowtok[row_base + tid];
    __syncthreads();

    const int srow = tid >> 4, scol = (tid & 15) * 4;
    const float* bg_base = w13 + ((size_t)e * I2 + (size_t)ct * BN) * HID;
    const float* bu_base = bg_base + (size_t)INTER * HID;

    const int w = tid >> 6, lane = tid & 63;
    const int wm = w >> 1, wn = w & 1;
    const int lrow = lane & 15, lk8 = (lane >> 4) * 8;

    f32x4 accg[2][4] = {};
    f32x4 accu[2][4] = {};

    for (int k0 = 0; k0 < HID; k0 += BK) {
        // stage A (64x64 f32 -> bf16), gathered rows
#pragma unroll
        for (int it = 0; it < 4; ++it) {
            int r = it * 16 + srow;
            int tok = toks[r];
            float4 v = make_float4(0.f, 0.f, 0.f, 0.f);
            if (tok >= 0)
                v = *reinterpret_cast<const float4*>(hidden + (size_t)tok * HID + k0 + scol);
            u16x4 o; o[0] = f2bf(v.x); o[1] = f2bf(v.y); o[2] = f2bf(v.z); o[3] = f2bf(v.w);
            *reinterpret_cast<u16x4*>(&As[r * 72 + scol]) = o;
        }
        // stage B gate & up (128x64 each)
#pragma unroll
        for (int it = 0; it < 8; ++it) {
            int r = it * 16 + srow;
            float4 vg = *reinterpret_cast<const float4*>(bg_base + (size_t)r * HID + k0 + scol);
            float4 vu = *reinterpret_cast<const float4*>(bu_base + (size_t)r * HID + k0 + scol);
            u16x4 og; og[0] = f2bf(vg.x); og[1] = f2bf(vg.y); og[2] = f2bf(vg.z); og[3] = f2bf(vg.w);
            u16x4 ou; ou[0] = f2bf(vu.x); ou[1] = f2bf(vu.y); ou[2] = f2bf(vu.z); ou[3] = f2bf(vu.w);
            *reinterpret_cast<u16x4*>(&Bgs[r * 72 + scol]) = og;
            *reinterpret_cast<u16x4*>(&Bus[r * 72 + scol]) = ou;
        }
        __syncthreads();
#pragma unroll
        for (int kk = 0; kk < 2; ++kk) {
            const int kof = kk * 32 + lk8;
            bf16x8 a0 = *reinterpret_cast<const bf16x8*>(&As[(wm * 32 + lrow) * 72 + kof]);
            bf16x8 a1 = *reinterpret_cast<const bf16x8*>(&As[(wm * 32 + 16 + lrow) * 72 + kof]);
            bf16x8 bg[4], bu[4];
#pragma unroll
            for (int fn = 0; fn < 4; ++fn) {
                bg[fn] = *reinterpret_cast<const bf16x8*>(&Bgs[(wn * 64 + fn * 16 + lrow) * 72 + kof]);
                bu[fn] = *reinterpret_cast<const bf16x8*>(&Bus[(wn * 64 + fn * 16 + lrow) * 72 + kof]);
            }
#pragma unroll
            for (int fn = 0; fn < 4; ++fn) {
                accg[0][fn] = __builtin_amdgcn_mfma_f32_16x16x32_bf16(a0, bg[fn], accg[0][fn], 0, 0, 0);
                accg[1][fn] = __builtin_amdgcn_mfma_f32_16x16x32_bf16(a1, bg[fn], accg[1][fn], 0, 0, 0);
                accu[0][fn] = __builtin_amdgcn_mfma_f32_16x16x32_bf16(a0, bu[fn], accu[0][fn], 0, 0, 0);
                accu[1][fn] = __builtin_amdgcn_mfma_f32_16x16x32_bf16(a1, bu[fn], accu[1][fn], 0, 0, 0);
            }
        }
        __syncthreads();
    }

    // epilogue: silu(gate)*up -> act (bf16)
#pragma unroll
    for (int fm = 0; fm < 2; ++fm)
#pragma unroll
        for (int fn = 0; fn < 4; ++fn)
#pragma unroll
            for (int j = 0; j < 4; ++j) {
                int row = wm * 32 + fm * 16 + (lane >> 4) * 4 + j;
                int col = wn * 64 + fn * 16 + lrow;
                float g = accg[fm][fn][j], u = accu[fm][fn][j];
                float sg = 1.f / (1.f + __expf(-g));
                float a = g * sg * u;
                act[(size_t)(row_base + row) * INTER + (size_t)ct * BN + col] = f2bf(a);
            }
}

// GEMM2: out[tok, h] += roww[slot] * act[slot,:] @ W2[e,h,:]
__global__ __launch_bounds__(256) void moe_gemm2(
        const u16* __restrict__ act, const float* __restrict__ w2,
        const int* __restrict__ mi, const float* __restrict__ mf,
        float* __restrict__ out) {
    const int tj = blockIdx.x, ct = blockIdx.y;
    if (tj >= mi[16]) return;
    const int e = mi[32 + 2 * tj], row_base = mi[32 + 2 * tj + 1];
    const int* rowtok = mi + 2560;
    const float* roww = mf + 5632;

    __shared__ u16 As[BM * 72];
    __shared__ u16 Bs[BN * 72];

    const int tid = threadIdx.x;
    const int srow = tid >> 4, scol = (tid & 15) * 4;
    const float* b_base = w2 + ((size_t)e * HID + (size_t)ct * BN) * INTER;

    const int w = tid >> 6, lane = tid & 63;
    const int wm = w >> 1, wn = w & 1;
    const int lrow = lane & 15, lk8 = (lane >> 4) * 8;

    f32x4 acc[2][4] = {};

    for (int k0 = 0; k0 < INTER; k0 += BK) {
        // stage A (bf16, no conversion): 64 rows x 64 cols
#pragma unroll
        for (int it = 0; it < 2; ++it) {
            int r = it * 32 + (tid >> 3);
            int c8 = (tid & 7) * 8;
            u16x8 v = *reinterpret_cast<const u16x8*>(act + (size_t)(row_base + r) * INTER + k0 + c8);
            *reinterpret_cast<u16x8*>(&As[r * 72 + c8]) = v;
        }
        // stage B (128x64 f32 -> bf16)
#pragma unroll
        for (int it = 0; it < 8; ++it) {
            int r = it * 16 + srow;
            float4 v = *reinterpret_cast<const float4*>(b_base + (size_t)r * INTER + k0 + scol);
            u16x4 o; o[0] = f2bf(v.x); o[1] = f2bf(v.y); o[2] = f2bf(v.z); o[3] = f2bf(v.w);
            *reinterpret_cast<u16x4*>(&Bs[r * 72 + scol]) = o;
        }
        __syncthreads();
#pragma unroll
        for (int kk = 0; kk < 2; ++kk) {
            const int kof = kk * 32 + lk8;
            bf16x8 a0 = *reinterpret_cast<const bf16x8*>(&As[(wm * 32 + lrow) * 72 + kof]);
            bf16x8 a1 = *reinterpret_cast<const bf16x8*>(&As[(wm * 32 + 16 + lrow) * 72 + kof]);
#pragma unroll
            for (int fn = 0; fn < 4; ++fn) {
                bf16x8 b = *reinterpret_cast<const bf16x8*>(&Bs[(wn * 64 + fn * 16 + lrow) * 72 + kof]);
                acc[0][fn] = __builtin_amdgcn_mfma_f32_16x16x32_bf16(a0, b, acc[0][fn], 0, 0, 0);
                acc[1][fn] = __builtin_amdgcn_mfma_f32_16x16x32_bf16(a1, b, acc[1][fn], 0, 0, 0);
            }
        }
        __syncthreads();
    }

#pragma unroll
    for (int fm = 0; fm < 2; ++fm)
#pragma unroll
        for (int fn = 0; fn < 4; ++fn)
#pragma unroll
            for (int j = 0; j < 4; ++j) {
                int row = wm * 32 + fm * 16 + (lane >> 4) * 4 + j;
                int col = wn * 64 + fn * 16 + lrow;
                int slot = row_base + row;
                int tok = rowtok[slot];
                if (tok >= 0) {
                    float v = acc[fm][fn][j] * roww[slot];
                    atomicAdd(out + (size_t)tok * HID + (size_t)ct * BN + col, v);
                }
            }
}

extern "C" void kernel_launch(void* const* d_in, const int* in_sizes, int n_in,
                              void* d_out, int out_size, void* d_ws, size_t ws_size,
                              hipStream_t stream) {
    const float* hidden = (const float*)d_in[0];
    const float* logits = (const float*)d_in[1];
    const float* w13    = (const float*)d_in[2];
    const float* w2     = (const float*)d_in[3];
    float* out = (float*)d_out;

    int*   mi  = (int*)d_ws;
    float* mf  = (float*)d_ws;
    u16*   act = (u16*)((char*)d_ws + 65536);

    hipMemsetAsync(d_ws, 0, 64, stream);                                // counts+run
    hipMemsetAsync(d_out, 0, (size_t)out_size * sizeof(float), stream); // accumulate target

    moe_router<<<dim3(T_TOK / 256), 256, 0, stream>>>(logits, mi, mf);
    moe_plan<<<dim3(1), 256, 0, stream>>>(mi);
    moe_scatter<<<dim3(T_TOK / 256), 256, 0, stream>>>(mi, mf);
    moe_gemm1<<<dim3(MAXTILES, INTER / BN), 256, 0, stream>>>(hidden, w13, mi, act);
    moe_gemm2<<<dim3(MAXTILES, HID / BN), 256, 0, stream>>>(act, w2, mi, mf, out);
}